// Round 12
// baseline (77.760 us; speedup 1.0000x reference)
//
#include <hip/hip_runtime.h>
#include <math.h>

// Problem constants
#define Bb 4
#define Cc 64
#define Hh 64
#define Ww 64
#define Ss 20

constexpr int XC = Hh * Ww * Ss;   // 81920  : x channel stride (floats)
constexpr int XH = Ww * Ss;        // 1280   : x row stride
constexpr int XW = Ss;             // 20     : x col stride
constexpr int XB = Cc * XC;        // 5242880: x batch stride
constexpr int NSITE = Bb * Hh * Ww;    // 16384
constexpr int PSMF  = NSITE * Ss;      // 327680 floats: softmax'd scores

// ws layout (floats): [0,576) Weff[tap][c'], [576,585) btap[tap],
//                     [640, 640+PSMF) psm  (softmax'd attention weights)

// ---------------------------------------------------------------------------
// Kernel 1: fold the K-branch 1x1 conv into the 3x3 conv.
// ---------------------------------------------------------------------------
__global__ void ct_fold_weights(const float* __restrict__ w1,
                                const float* __restrict__ b1,
                                const float* __restrict__ w2,
                                float* __restrict__ ws) {
    int tid = threadIdx.x;
    if (tid < 576) {
        int tap = tid >> 6, cp = tid & 63;
        float acc = 0.f;
        #pragma unroll 8
        for (int c = 0; c < 64; ++c)
            acc += w2[(64 + c) * 9 + tap] * w1[(64 + c) * 64 + cp];
        ws[tid] = acc;
    } else if (tid < 585) {
        int tap = tid - 576;
        float acc = 0.f;
        for (int c = 0; c < 64; ++c)
            acc += w2[(64 + c) * 9 + tap] * b1[64 + c];
        ws[576 + tap] = acc;
    }
}

// ---------------------------------------------------------------------------
// Kernel 2: conv + softmax, with EXPLICIT register double-buffering.
// Block = (b, h, wq): 16 sites. 320 threads = cg(4) x w16(16) x t4(5).
// grid 1024 -> 4 blocks/CU = 20 waves/CU. Each thread: 144-load clamped
// gather, but channels c+2/c+3 are prefetched into pvA/pvB while c/c+1 are
// consumed -> >=18 loads guaranteed in flight per thread (the warm-L3
// latency-bound diagnosis from R11: VALUBusy 12%, HBM~0, ~2-4 loads in
// flight under compiler scheduling). All pvA/pvB indices compile-time.
// Tail: LDS reduce (320 = 16 sites x 20 t exactly) + bias, 16-thread
// softmax, coalesced 1280 B psm write.
// ---------------------------------------------------------------------------
__global__ __launch_bounds__(320, 5) void ct_conv_sm(
        const float* __restrict__ x,
        const float* __restrict__ ws,
        float* __restrict__ psm) {
    __shared__ float weff[576];
    __shared__ float btL[9];
    __shared__ float bkp[4][16][20];
    __shared__ float psmL[16][20];
    int tid = threadIdx.x;

    for (int i = tid; i < 576; i += 320) weff[i] = ws[i];
    if (tid < 9) btL[tid] = ws[576 + tid];

    // 1024 blocks = b(4) x h(64) x wq(4); XCD owns contiguous 128 -> h-halo reuse
    int g = (blockIdx.x & 7) * 128 + (blockIdx.x >> 3);
    int wq = g & 3;
    int h  = (g >> 2) & 63;
    int b  = g >> 8;

    int cg = tid / 80, r = tid % 80;
    int w16 = r / 5, t4 = r % 5;
    int w = wq * 16 + w16;

    float vmask[9];
    int off[9];
    #pragma unroll
    for (int dh = 0; dh < 3; ++dh) {
        int hh = h + dh - 1;
        float hv = (hh >= 0 && hh < Hh) ? 1.f : 0.f;
        int hcl = hh < 0 ? 0 : (hh > Hh - 1 ? Hh - 1 : hh);
        #pragma unroll
        for (int dw = 0; dw < 3; ++dw) {
            int wc = w + dw - 1;
            float wvd = (wc >= 0 && wc < Ww) ? 1.f : 0.f;
            int wcl = wc < 0 ? 0 : (wc > Ww - 1 ? Ww - 1 : wc);
            vmask[dh * 3 + dw] = hv * wvd;
            off[dh * 3 + dw] = hcl * XH + wcl * XW;
        }
    }
    __syncthreads();   // weff ready

    const float* xb = x + b * XB + cg * 16 * XC + t4 * 4;
    float4 acc = make_float4(0.f, 0.f, 0.f, 0.f);
    float4 pvA[9], pvB[9];
    #pragma unroll
    for (int tap = 0; tap < 9; ++tap)
        pvA[tap] = *reinterpret_cast<const float4*>(xb + off[tap]);
    #pragma unroll
    for (int tap = 0; tap < 9; ++tap)
        pvB[tap] = *reinterpret_cast<const float4*>(xb + XC + off[tap]);

    #pragma unroll 1
    for (int c = 0; c < 16; c += 2) {
        // prefetch sources (clamped at the tail; extra loads never accumulated)
        const float* xn2 = xb + (c + 2 < 16 ? c + 2 : c) * XC;
        const float* xn3 = xb + (c + 3 < 16 ? c + 3 : c + 1) * XC;

        #pragma unroll
        for (int tap = 0; tap < 9; ++tap) {
            float wv = weff[tap * 64 + cg * 16 + c] * vmask[tap];
            float4 v = pvA[tap];
            acc.x = fmaf(wv, v.x, acc.x);
            acc.y = fmaf(wv, v.y, acc.y);
            acc.z = fmaf(wv, v.z, acc.z);
            acc.w = fmaf(wv, v.w, acc.w);
        }
        #pragma unroll
        for (int tap = 0; tap < 9; ++tap)
            pvA[tap] = *reinterpret_cast<const float4*>(xn2 + off[tap]);

        #pragma unroll
        for (int tap = 0; tap < 9; ++tap) {
            float wv = weff[tap * 64 + cg * 16 + c + 1] * vmask[tap];
            float4 v = pvB[tap];
            acc.x = fmaf(wv, v.x, acc.x);
            acc.y = fmaf(wv, v.y, acc.y);
            acc.z = fmaf(wv, v.z, acc.z);
            acc.w = fmaf(wv, v.w, acc.w);
        }
        #pragma unroll
        for (int tap = 0; tap < 9; ++tap)
            pvB[tap] = *reinterpret_cast<const float4*>(xn3 + off[tap]);
    }

    *reinterpret_cast<float4*>(&bkp[cg][w16][t4 * 4]) = acc;
    __syncthreads();

    // reduce 4 channel-group partials + per-site valid-tap bias
    {
        int sw = tid / 20, t = tid % 20;      // 320 = 16*20 exactly
        float v = bkp[0][sw][t] + bkp[1][sw][t] + bkp[2][sw][t] + bkp[3][sw][t];
        int wsit = wq * 16 + sw;
        float bs = 0.f;
        #pragma unroll
        for (int dh = 0; dh < 3; ++dh) {
            int hh = h + dh - 1;
            if (hh < 0 || hh >= Hh) continue;
            #pragma unroll
            for (int dw = 0; dw < 3; ++dw) {
                int wc = wsit + dw - 1;
                if (wc < 0 || wc >= Ww) continue;
                bs += btL[dh * 3 + dw];
            }
        }
        psmL[sw][t] = v + bs;
    }
    __syncthreads();

    if (tid < 16) {                           // softmax per site
        float p[20];
        #pragma unroll
        for (int i = 0; i < 20; ++i) p[i] = psmL[tid][i];
        float m = p[0];
        #pragma unroll
        for (int i = 1; i < 20; ++i) m = fmaxf(m, p[i]);
        float ssum = 0.f;
        #pragma unroll
        for (int i = 0; i < 20; ++i) { p[i] = __expf(p[i] - m); ssum += p[i]; }
        float inv = 1.f / ssum;
        #pragma unroll
        for (int i = 0; i < 20; ++i) psmL[tid][i] = p[i] * inv;
    }
    __syncthreads();

    {
        int sw = tid / 20, t = tid % 20;
        int base = (b * 4096 + h * 64 + wq * 16) * 20;
        psm[base + tid] = psmL[sw][t];        // contiguous 1280 B per block
    }
}

// ---------------------------------------------------------------------------
// Kernel 3 (attn-lite, proven R11): block = 8 sites, 256 threads, grid 2048.
// Load psm, xbar -> R (LDS-transposed w1v, stride 65) -> broadcast store.
// ---------------------------------------------------------------------------
__global__ __launch_bounds__(256) void ct_attn_lite(
        const float* __restrict__ x,
        const float* __restrict__ w1,
        const float* __restrict__ b1,
        const float* __restrict__ psm,
        float* __restrict__ out) {
    __shared__ float w1t[64 * 65];   // w1t[cp*65 + c] = w1v[c][cp]
    __shared__ float psmL[8][20];
    __shared__ float xsh[8][65];
    int tid = threadIdx.x;
    #pragma unroll
    for (int k = 0; k < 16; ++k) {
        int j = tid + k * 256;            // coalesced global read
        int r = j >> 6, q = j & 63;
        w1t[q * 65 + r] = w1[8192 + j];   // w1v row r, col q
    }

    int site0 = blockIdx.x * 8;
    if (tid < 160) {
        int si = tid / 20, i = tid % 20;
        psmL[si][i] = psm[(site0 + si) * 20 + i];
    }
    __syncthreads();

    int si = tid & 7, cg = tid >> 3;
    int site = site0 + si;
    int b = site >> 12, hw = site & 4095;

    #pragma unroll
    for (int k = 0; k < 2; ++k) {
        int c = cg * 2 + k;
        const float* xp = x + (b * 64 + c) * XC + hw * 20;
        float xbv = 0.f;
        #pragma unroll
        for (int i = 0; i < 5; ++i) {
            float4 xv = reinterpret_cast<const float4*>(xp)[i];
            xbv = fmaf(psmL[si][4 * i],     xv.x, xbv);
            xbv = fmaf(psmL[si][4 * i + 1], xv.y, xbv);
            xbv = fmaf(psmL[si][4 * i + 2], xv.z, xbv);
            xbv = fmaf(psmL[si][4 * i + 3], xv.w, xbv);
        }
        xsh[si][c] = xbv;
    }
    __syncthreads();

    #pragma unroll
    for (int k = 0; k < 2; ++k) {
        int c = cg * 2 + k;
        float R = b1[128 + c];
        #pragma unroll 8
        for (int cp = 0; cp < 64; ++cp)
            R = fmaf(w1t[cp * 65 + c], xsh[si][cp], R);
        float* op = out + (b * 64 + c) * XC + hw * 20;
        float4 rv = make_float4(R, R, R, R);
        #pragma unroll
        for (int s4 = 0; s4 < 5; ++s4)
            reinterpret_cast<float4*>(op)[s4] = rv;
    }
}

extern "C" void kernel_launch(void* const* d_in, const int* in_sizes, int n_in,
                              void* d_out, int out_size, void* d_ws, size_t ws_size,
                              hipStream_t stream) {
    const float* x  = (const float*)d_in[0];
    const float* w1 = (const float*)d_in[1];
    const float* b1 = (const float*)d_in[2];
    const float* w2 = (const float*)d_in[3];
    // d_in[4] (b2) is mathematically dead: it cancels in the softmax over t.
    float* ws  = (float*)d_ws;
    float* psm = ws + 640;
    float* out = (float*)d_out;

    ct_fold_weights<<<1, 640, 0, stream>>>(w1, b1, w2, ws);
    ct_conv_sm<<<1024, 320, 0, stream>>>(x, ws, psm);
    ct_attn_lite<<<2048, 256, 0, stream>>>(x, w1, b1, psm, out);
}